// Round 9
// baseline (96.488 us; speedup 1.0000x reference)
//
#include <hip/hip_runtime.h>

// CRF loss on MI355X.
//   Z-part: exp-domain forward algorithm. exp(step matrix) = diag(g_t)*E with
//   g_t[i]=exp(sigmoid(h[t,b,i])), E=exp(trans)*2^-4 (corrected by 4*ln2*len
//   at the end). L=1024 in 16 chunks of 64 steps.
//   Phase 1 (R9): block = 16 consecutive b's x one chunk. Staging reads h in
//   1KB CONTIGUOUS t-rows (one dwordx4 per wave per row) -- R3-R8 post-mortem:
//   the invariant ~70us wall was h staged in 64-256B segments at 128KB stride
//   (~2 TB/s effective); compute/latency/DS theories all exonerated by
//   elimination. Compute: unchanged proven R8 asm loop (RUN_SEG), 4 b-chains
//   per warp, generalized variable-length driver.
//   Phase 2: one wave per b combines 16 chunk matrices (power-of-2 renorm).
//   S-part: gather-sum of trans[y0[t+1],y0[t]]*mask[t].
// ws layout: [0,8KB) len, [8KB,16KB) S, [16KB,+16MB) P bf16.

typedef unsigned int u32;
typedef float f32x4 __attribute__((ext_vector_type(4)));
typedef short s16x4 __attribute__((ext_vector_type(4)));
typedef unsigned int u32x2 __attribute__((ext_vector_type(2)));

#define LOG2E 1.4426950408889634f
#define LN2   0.6931471805599453f
#define Bsz   2048
#define Lsz   1024
#define BT    32768   /* Bsz*16 floats per timestep */
#define BSTR  556     /* gbuf b-stride in u32: %4==0 (b128-aligned), mod32=12 */

#if __has_builtin(__builtin_amdgcn_exp2f)
__device__ __forceinline__ float exp2x(float x){ return __builtin_amdgcn_exp2f(x); }
#else
__device__ __forceinline__ float exp2x(float x){ return exp2f(x); }
#endif
#if __has_builtin(__builtin_amdgcn_logf)
__device__ __forceinline__ float log2x(float x){ return __builtin_amdgcn_logf(x); }
#else
__device__ __forceinline__ float log2x(float x){ return log2f(x); }
#endif
#if __has_builtin(__builtin_amdgcn_rcpf)
__device__ __forceinline__ float rcpx(float x){ return __builtin_amdgcn_rcpf(x); }
#else
__device__ __forceinline__ float rcpx(float x){ return 1.0f/x; }
#endif

__device__ __forceinline__ u32 cvtpk_bf16(float lo, float hi){
  u32 r;
  asm("v_cvt_pk_bf16_f32 %0, %1, %2" : "=v"(r) : "v"(lo), "v"(hi));
  return r;
}

// R1-proven single MFMA with hazard padding (odd-tail steps).
__device__ __forceinline__ f32x4 mfma16(s16x4 a, s16x4 b, f32x4 c){
  f32x4 d;
  asm volatile("s_nop 1\n\t"
      "v_mfma_f32_16x16x16_bf16 %0, %1, %2, %3\n\t"
      "s_nop 7\n\t"
      "s_nop 7"
      : "=&v"(d) : "v"(a), "v"(b), "v"(c));
  return d;
}

// R8-proven dual-chain K-loop, fixed regs v32-v61 (see R8 notes).
#define RUN_SEG(CNT, A0, A1, B0X, B0Y, B1X, B1Y, ELO, EHI)                     \
  asm volatile(                                                                \
    "s_waitcnt lgkmcnt(0)\n\t"                                                 \
    "v_mov_b32 v40, %[b0x]\n\t"                                                \
    "v_mov_b32 v41, %[b0y]\n\t"                                                \
    "v_mov_b32 v42, %[b1x]\n\t"                                                \
    "v_mov_b32 v43, %[b1y]\n\t"                                                \
    "v_mov_b32 v56, %[elo]\n\t"                                                \
    "v_mov_b32 v57, %[ehi]\n\t"                                                \
    "v_mov_b32 v58, 0\n\t"                                                     \
    "v_mov_b32 v59, 0\n\t"                                                     \
    "v_mov_b32 v60, 0\n\t"                                                     \
    "v_mov_b32 v61, 0\n\t"                                                     \
    ".LP%=:\n\t"                                                               \
    "ds_read_b128 v[44:47], %[a0]\n\t"                                         \
    "ds_read_b128 v[48:51], %[a1]\n\t"                                         \
    "v_add_u32 %[a0], 16, %[a0]\n\t"                                           \
    "v_add_u32 %[a1], 16, %[a1]\n\t"                                           \
    "s_waitcnt lgkmcnt(0)\n\t"                                                 \
    "s_nop 1\n\t"                                                              \
    "v_mfma_f32_16x16x16_bf16 v[32:35], v[56:57], v[40:41], v[58:61]\n\t"      \
    "v_mfma_f32_16x16x16_bf16 v[36:39], v[56:57], v[42:43], v[58:61]\n\t"      \
    "v_lshlrev_b32 v52, 16, v44\n\t"                                           \
    "v_and_b32 v53, 0xffff0000, v44\n\t"                                       \
    "v_lshlrev_b32 v54, 16, v45\n\t"                                           \
    "v_and_b32 v55, 0xffff0000, v45\n\t"                                       \
    "s_nop 6\n\t"                                                              \
    "v_mul_f32 v52, v32, v52\n\t"                                              \
    "v_mul_f32 v53, v33, v53\n\t"                                              \
    "v_mul_f32 v54, v34, v54\n\t"                                              \
    "v_mul_f32 v55, v35, v55\n\t"                                              \
    "v_cvt_pk_bf16_f32 v40, v52, v53\n\t"                                      \
    "v_cvt_pk_bf16_f32 v41, v54, v55\n\t"                                      \
    "v_lshlrev_b32 v52, 16, v48\n\t"                                           \
    "v_and_b32 v53, 0xffff0000, v48\n\t"                                       \
    "v_lshlrev_b32 v54, 16, v49\n\t"                                           \
    "v_and_b32 v55, 0xffff0000, v49\n\t"                                       \
    "v_mul_f32 v52, v36, v52\n\t"                                              \
    "v_mul_f32 v53, v37, v53\n\t"                                              \
    "v_mul_f32 v54, v38, v54\n\t"                                              \
    "v_mul_f32 v55, v39, v55\n\t"                                              \
    "v_cvt_pk_bf16_f32 v42, v52, v53\n\t"                                      \
    "v_cvt_pk_bf16_f32 v43, v54, v55\n\t"                                      \
    "s_nop 1\n\t"                                                              \
    "v_mfma_f32_16x16x16_bf16 v[32:35], v[56:57], v[40:41], v[58:61]\n\t"      \
    "v_mfma_f32_16x16x16_bf16 v[36:39], v[56:57], v[42:43], v[58:61]\n\t"      \
    "v_lshlrev_b32 v52, 16, v46\n\t"                                           \
    "v_and_b32 v53, 0xffff0000, v46\n\t"                                       \
    "v_lshlrev_b32 v54, 16, v47\n\t"                                           \
    "v_and_b32 v55, 0xffff0000, v47\n\t"                                       \
    "s_nop 6\n\t"                                                              \
    "v_mul_f32 v52, v32, v52\n\t"                                              \
    "v_mul_f32 v53, v33, v53\n\t"                                              \
    "v_mul_f32 v54, v34, v54\n\t"                                              \
    "v_mul_f32 v55, v35, v55\n\t"                                              \
    "v_cvt_pk_bf16_f32 v40, v52, v53\n\t"                                      \
    "v_cvt_pk_bf16_f32 v41, v54, v55\n\t"                                      \
    "v_lshlrev_b32 v52, 16, v50\n\t"                                           \
    "v_and_b32 v53, 0xffff0000, v50\n\t"                                       \
    "v_lshlrev_b32 v54, 16, v51\n\t"                                           \
    "v_and_b32 v55, 0xffff0000, v51\n\t"                                       \
    "v_mul_f32 v52, v36, v52\n\t"                                              \
    "v_mul_f32 v53, v37, v53\n\t"                                              \
    "v_mul_f32 v54, v38, v54\n\t"                                              \
    "v_mul_f32 v55, v39, v55\n\t"                                              \
    "v_cvt_pk_bf16_f32 v42, v52, v53\n\t"                                      \
    "v_cvt_pk_bf16_f32 v43, v54, v55\n\t"                                      \
    "s_sub_u32 %[cnt], %[cnt], 1\n\t"                                          \
    "s_cmp_lg_u32 %[cnt], 0\n\t"                                               \
    "s_cbranch_scc1 .LP%=\n\t"                                                 \
    "v_mov_b32 %[b0x], v40\n\t"                                                \
    "v_mov_b32 %[b0y], v41\n\t"                                                \
    "v_mov_b32 %[b1x], v42\n\t"                                                \
    "v_mov_b32 %[b1y], v43"                                                    \
    : [a0]"+v"(A0), [a1]"+v"(A1), [cnt]"+s"(CNT),                              \
      [b0x]"+v"(B0X), [b0y]"+v"(B0Y), [b1x]"+v"(B1X), [b1y]"+v"(B1Y)           \
    : [elo]"v"(ELO), [ehi]"v"(EHI)                                             \
    : "memory",                                                                \
      "v32","v33","v34","v35","v36","v37","v38","v39",                         \
      "v40","v41","v42","v43","v44","v45","v46","v47",                         \
      "v48","v49","v50","v51","v52","v53","v54","v55",                         \
      "v56","v57","v58","v59","v60","v61")

__global__ __launch_bounds__(256) void k_zero(float* lenw, float* Sw, float* out){
  int i = blockIdx.x*256 + threadIdx.x;
  if (i < Bsz) lenw[i] = 0.f;
  else if (i < 2*Bsz) Sw[i - Bsz] = 0.f;
  if (i == 0) out[0] = 0.f;
}

// lengths[b] = sum_t mask[t,b]; S[b] partial = sum_t trans[y0[t+1],y0[t]]*mask[t]
__global__ __launch_bounds__(256) void k_score(const int* __restrict__ y0,
    const float* __restrict__ mask, const float* __restrict__ trans,
    float* __restrict__ lenw, float* __restrict__ Sw){
  __shared__ float Tt[256];
  Tt[threadIdx.x] = trans[threadIdx.x];
  __syncthreads();
  int gid = blockIdx.x*256 + threadIdx.x;   // 65536 threads: b fast, tc slow
  int b  = gid & (Bsz-1);
  int tc = gid >> 11;                        // 0..31, 32 t's each
  int t0 = tc * 32;
  float lacc = 0.f, sacc = 0.f;
  int yc = y0[t0*Bsz + b];
  #pragma unroll 4
  for (int t = t0; t < t0+32; ++t) {
    float m = mask[t*Bsz + b];
    int yn = y0[(t+1)*Bsz + b];
    lacc += m;
    if (t <= Lsz-2) sacc += m * Tt[yn*16 + yc];
    yc = yn;
  }
  atomicAdd(&lenw[b], lacc);
  atomicAdd(&Sw[b], sacc);
}

// Phase 1: block = (bg = bid&127 -> b's 16bg..16bg+15) x (chunk c = bid>>7).
__global__ __launch_bounds__(256) void k_phase1(const float* __restrict__ h,
    const float* __restrict__ trans, const float* __restrict__ lenw,
    u32x2* __restrict__ Pout){
  // bf16 g: gbuf[b*556 + q*132 + 2t + half]; u32 = (tag 4q+2h', 4q+2h'+1) at
  // time t. Chain b128 reads: 4 distinct addrs (per q), 16-lane broadcast ->
  // conflict-free. Staging b64 writes: <=4-way (BSTR mod 32 = 12), cold path.
  __shared__ __align__(16) u32 gbuf[16*BSTR];
  int bg   = blockIdx.x & 127;
  int c    = blockIdx.x >> 7;    // 0..15
  int warp = threadIdx.x >> 6;
  int lane = threadIdx.x & 63;
  int cl   = lane & 15;
  int grp  = lane >> 4;
  int t0   = c << 6;
  int gb0  = bg*16 + warp*4;     // this warp's 4 b's

  int act[4]; int any = 0;
  #pragma unroll
  for (int i = 0; i < 4; ++i) {
    int a = (int)(lenw[gb0 + i] + 0.5f) - t0;
    a = a < 0 ? 0 : (a > 64 ? 64 : a);
    act[i] = a; any |= a;
  }
  if (!__syncthreads_or(any)) return;   // whole block past every length

  // ---- stage: warp w loads t-rows t = 4i+w. One float4/lane = 1KB/row,
  // fully contiguous in h (fixed t: [b][tag] plane). lane -> b=lane>>2,
  // tags 4(lane&3)..+3.
  {
    int bq = lane >> 2, q = lane & 3;
    const float* hp = h + (size_t)t0*BT + bg*256 + 4*lane;
    u32* wp = &gbuf[bq*BSTR + q*132];
    #pragma unroll
    for (int i = 0; i < 16; ++i) {
      int t = 4*i + warp;
      const float4 hv = *(const float4*)(hp + (size_t)t*BT);
      float g0 = exp2x(rcpx(1.f + exp2x(hv.x * (-LOG2E))) * LOG2E);
      float g1 = exp2x(rcpx(1.f + exp2x(hv.y * (-LOG2E))) * LOG2E);
      float g2 = exp2x(rcpx(1.f + exp2x(hv.z * (-LOG2E))) * LOG2E);
      float g3 = exp2x(rcpx(1.f + exp2x(hv.w * (-LOG2E))) * LOG2E);
      u32x2 pk; pk.x = cvtpk_bf16(g0, g1); pk.y = cvtpk_bf16(g2, g3);
      *(u32x2*)&wp[2*t] = pk;
    }
  }
  __syncthreads();

  // EA = E row cl, k-cols grp*4..+3, scaled 2^-4, bf16.
  u32 elo, ehi;
  {
    const float* tp = trans + cl*16 + grp*4;
    float E0 = exp2x(tp[0]*LOG2E) * 0.0625f;
    float E1 = exp2x(tp[1]*LOG2E) * 0.0625f;
    float E2 = exp2x(tp[2]*LOG2E) * 0.0625f;
    float E3 = exp2x(tp[3]*LOG2E) * 0.0625f;
    elo = cvtpk_bf16(E0, E1);
    ehi = cvtpk_bf16(E2, E3);
  }
  int k0 = grp*4;
  const u32 ibx = ((k0+0)==cl ? 0x3F80u : 0u) | (((k0+1)==cl ? 0x3F80u : 0u) << 16);
  const u32 iby = ((k0+2)==cl ? 0x3F80u : 0u) | (((k0+3)==cl ? 0x3F80u : 0u) << 16);
  const f32x4 z4 = {0.f,0.f,0.f,0.f};

  // single chain step at time t (R8-proven odd-tail body)
  #define STEP1(BX, BY, GB, T) do {                                        \
    u32x2 gw = *(const u32x2*)&(GB)[2*(T)];                                \
    float f0 = __uint_as_float(gw.x << 16);                                \
    float f1 = __uint_as_float(gw.x & 0xffff0000u);                        \
    float f2 = __uint_as_float(gw.y << 16);                                \
    float f3 = __uint_as_float(gw.y & 0xffff0000u);                        \
    union { u32 u[2]; s16x4 v; } EAv, Bf;                                  \
    EAv.u[0] = elo; EAv.u[1] = ehi;                                        \
    Bf.u[0] = (BX); Bf.u[1] = (BY);                                        \
    f32x4 d = mfma16(EAv.v, Bf.v, z4);                                     \
    (BX) = cvtpk_bf16(d.x*f0, d.y*f1);                                     \
    (BY) = cvtpk_bf16(d.z*f2, d.w*f3);                                     \
  } while (0)

  #pragma unroll
  for (int pr = 0; pr < 2; ++pr) {
    int iA = 2*pr, iB = 2*pr + 1;
    int rA = act[iA], rB = act[iB];
    if ((rA | rB) == 0) continue;
    u32* gbA = &gbuf[(warp*4 + iA)*BSTR + grp*132];
    u32* gbB = &gbuf[(warp*4 + iB)*BSTR + grp*132];
    u32 aA = (u32)(unsigned long long)gbA;
    u32 aB = (u32)(unsigned long long)gbB;
    u32 bAx = ibx, bAy = iby, bBx = ibx, bBy = iby;
    int m = rA < rB ? rA : rB;
    int M = rA < rB ? rB : rA;
    int p1 = m >> 1;
    if (p1 > 0) {
      u32 cnt = (u32)__builtin_amdgcn_readfirstlane(p1);
      RUN_SEG(cnt, aA, aB, bAx, bAy, bBx, bBy, elo, ehi);
    }
    int te = 2*p1;
    if (m & 1) {                      // only chains ENDING at m take odd step
      if (rA == m) STEP1(bAx, bAy, gbA, te);
      if (rB == m) STEP1(bBx, bBy, gbB, te);
    }
    if (rA == m && rA > 0)
      Pout[((size_t)(gb0 + iA)*16 + c)*64 + lane] = (u32x2){bAx, bAy};
    if (rB == m && rB > 0)
      Pout[((size_t)(gb0 + iB)*16 + c)*64 + lane] = (u32x2){bBx, bBy};
    if (M > m) {                      // longer chain continues from even te
      int rem = M - te;
      int p2 = rem >> 1;
      if (rA > rB) {
        if (p2 > 0) {
          u32 cnt = (u32)__builtin_amdgcn_readfirstlane(p2);
          RUN_SEG(cnt, aA, aB, bAx, bAy, bBx, bBy, elo, ehi);
        }
        if (rem & 1) STEP1(bAx, bAy, gbA, te + 2*p2);
        Pout[((size_t)(gb0 + iA)*16 + c)*64 + lane] = (u32x2){bAx, bAy};
      } else {
        if (p2 > 0) {
          u32 cnt = (u32)__builtin_amdgcn_readfirstlane(p2);
          RUN_SEG(cnt, aB, aA, bBx, bBy, bAx, bAy, elo, ehi);
        }
        if (rem & 1) STEP1(bBx, bBy, gbB, te + 2*p2);
        Pout[((size_t)(gb0 + iB)*16 + c)*64 + lane] = (u32x2){bBx, bBy};
      }
    }
  }
  #undef STEP1
}

// Phase 2: wave per b. v <- P_c * v with power-of-2 renorm; then final lse.
__global__ __launch_bounds__(256) void k_phase2(const u32x2* __restrict__ P,
    const float* __restrict__ trans, const float* __restrict__ lenw,
    const float* __restrict__ Sw, const int* __restrict__ y0,
    float* __restrict__ out){
  __shared__ float red[4];
  int b = blockIdx.x*4 + (threadIdx.x >> 6);
  int lane = threadIdx.x & 63;
  int cl = lane & 15, grp = lane >> 4;
  int len = (int)(lenw[b] + 0.5f);
  float v = (cl == 1) ? 1.f : 0.f;    // exp(Z0): one-hot at SOS_IDX=1
  float lsc = 0.f;                    // accumulated log2 scale
  int nch = (len + 63) >> 6;
  const u32x2* Pb = P + (size_t)b*16*64;
  int srcaddr = (cl >> 2) << 6;       // bpermute byte addr of lane (cl>>2)*16
  int msel = cl & 3;
  for (int c = 0; c < nch; ++c) {
    u32x2 pw = Pb[c*64 + lane];       // P[grp*4+m, cl] bf16 pairs
    float p0 = __uint_as_float(pw.x << 16);
    float p1 = __uint_as_float(pw.x & 0xffff0000u);
    float p2 = __uint_as_float(pw.y << 16);
    float p3 = __uint_as_float(pw.y & 0xffff0000u);
    float q0 = p0*v, q1 = p1*v, q2 = p2*v, q3 = p3*v;
    #pragma unroll
    for (int mk = 1; mk <= 8; mk <<= 1) {
      q0 += __shfl_xor(q0, mk);
      q1 += __shfl_xor(q1, mk);
      q2 += __shfl_xor(q2, mk);
      q3 += __shfl_xor(q3, mk);
    }
    float t0v = __int_as_float(__builtin_amdgcn_ds_bpermute(srcaddr, __float_as_int(q0)));
    float t1v = __int_as_float(__builtin_amdgcn_ds_bpermute(srcaddr, __float_as_int(q1)));
    float t2v = __int_as_float(__builtin_amdgcn_ds_bpermute(srcaddr, __float_as_int(q2)));
    float t3v = __int_as_float(__builtin_amdgcn_ds_bpermute(srcaddr, __float_as_int(q3)));
    float vn = (msel==0) ? t0v : (msel==1) ? t1v : (msel==2) ? t2v : t3v;
    float gm = fmaxf(fmaxf(q0,q1), fmaxf(q2,q3));
    gm = fmaxf(gm, __shfl_xor(gm, 16));
    gm = fmaxf(gm, __shfl_xor(gm, 32));
    int eb = (int)((__float_as_uint(gm) >> 23) & 0xff) - 127;
    float sc = __uint_as_float((u32)(127 - eb) << 23);
    v = vn * sc;
    lsc += (float)eb;
  }
  float eE = exp2x(trans[32 + cl] * LOG2E);
  float num = v * eE;
  num += __shfl_xor(num, 1);
  num += __shfl_xor(num, 2);
  num += __shfl_xor(num, 4);
  num += __shfl_xor(num, 8);
  if (lane == 0) {
    float Z = (log2x(num) + lsc + 4.f*(float)len) * LN2;
    int lastTag = y0[(size_t)len*Bsz + b];
    float Sb = Sw[b] + trans[lastTag];     // trans[PAD=0, lastTag]
    red[threadIdx.x >> 6] = (Z - Sb) * (1.f/(float)Bsz);
  }
  __syncthreads();
  if (threadIdx.x == 0) {
    atomicAdd(out, red[0] + red[1] + red[2] + red[3]);
  }
}

extern "C" void kernel_launch(void* const* d_in, const int* in_sizes, int n_in,
                              void* d_out, int out_size, void* d_ws, size_t ws_size,
                              hipStream_t stream) {
  const float* h     = (const float*)d_in[0];
  const int*   y0    = (const int*)d_in[1];
  const float* mask  = (const float*)d_in[2];
  const float* trans = (const float*)d_in[3];
  float* out  = (float*)d_out;
  float* lenw = (float*)d_ws;
  float* Sw   = lenw + Bsz;
  u32x2* P    = (u32x2*)((char*)d_ws + 16384);

  k_zero  <<<16,   256, 0, stream>>>(lenw, Sw, out);
  k_score <<<256,  256, 0, stream>>>(y0, mask, trans, lenw, Sw);
  k_phase1<<<2048, 256, 0, stream>>>(h, trans, lenw, P);
  k_phase2<<<512,  256, 0, stream>>>(P, trans, lenw, Sw, y0, out);
}

// Round 10
// 84.511 us; speedup vs baseline: 1.1417x; 1.1417x over previous
//
#include <hip/hip_runtime.h>

// CRF loss on MI355X.
//   Z-part: exp-domain forward algorithm. exp(step matrix) = diag(g_t)*E with
//   g_t[i]=exp(sigmoid(h[t,b,i])), E=exp(trans)*2^-4 (corrected by 4*ln2*len
//   at the end). L=1024 in 16 chunks of 64 steps.
//   Phase 1 (R10): wave per (b,chunk), chunk-major (L3-warm, R3/R5/R6-proven).
//   TREE-LITE: each 4-step group = V <- N2*(N1*V) with N1=Em1*Em0, N2=Em3*Em2
//   computed as INDEPENDENT MFMAs (R9 post-mortem: 125 cyc/step == per-wave
//   serial latency wall; issue cost exonerated by R8's hand asm). Layout
//   identity Afrag(X)=Bfrag(X^T) makes both leaf forms elementwise scalings
//   of fixed E-frags -- no cross-lane. One fused fixed-reg asm block per
//   4 steps: serial ~40 cyc/step vs ~125 measured for the chain.
//   Phase 2: one wave per b combines 16 chunk matrices (power-of-2 renorm).
//   S-part: gather-sum of trans[y0[t+1],y0[t]]*mask[t].
// ws layout: [0,8KB) len, [8KB,16KB) S, [16KB,+16MB) P bf16.

typedef unsigned int u32;
typedef float f32x4 __attribute__((ext_vector_type(4)));
typedef short s16x4 __attribute__((ext_vector_type(4)));
typedef unsigned int u32x2 __attribute__((ext_vector_type(2)));

#define LOG2E 1.4426950408889634f
#define LN2   0.6931471805599453f
#define Bsz   2048
#define Lsz   1024
#define BT    32768   /* Bsz*16 floats per timestep */
#define GSTR  20      /* g row stride in floats: 80B = 5*16B -> b128-aligned */

#if __has_builtin(__builtin_amdgcn_exp2f)
__device__ __forceinline__ float exp2x(float x){ return __builtin_amdgcn_exp2f(x); }
#else
__device__ __forceinline__ float exp2x(float x){ return exp2f(x); }
#endif
#if __has_builtin(__builtin_amdgcn_logf)
__device__ __forceinline__ float log2x(float x){ return __builtin_amdgcn_logf(x); }
#else
__device__ __forceinline__ float log2x(float x){ return log2f(x); }
#endif
#if __has_builtin(__builtin_amdgcn_rcpf)
__device__ __forceinline__ float rcpx(float x){ return __builtin_amdgcn_rcpf(x); }
#else
__device__ __forceinline__ float rcpx(float x){ return 1.0f/x; }
#endif

__device__ __forceinline__ u32 cvtpk_bf16(float lo, float hi){
  u32 r;
  asm("v_cvt_pk_bf16_f32 %0, %1, %2" : "=v"(r) : "v"(lo), "v"(hi));
  return r;
}

// R1-proven single MFMA with hazard padding (tail steps).
__device__ __forceinline__ f32x4 mfma16(s16x4 a, s16x4 b, f32x4 c){
  f32x4 d;
  asm volatile("s_nop 1\n\t"
      "v_mfma_f32_16x16x16_bf16 %0, %1, %2, %3\n\t"
      "s_nop 7\n\t"
      "s_nop 7"
      : "=&v"(d) : "v"(a), "v"(b), "v"(c));
  return d;
}

// Fused 4-step tree block. Scratch fixed v40-v53; operands compiler-alloc'd.
// N1^T = mfma(L0, L1); N2^T = mfma(L2, L3)  [independent, back-to-back]
// W = mfma(N1A, V); V' = mfma(N2A, W).
// Hazard margins mirror R1's proven 16-cycle MFMA->VALU-read distance:
//  - mfma1 D read: mfma2(8) + 2x s_nop7(16) = 24 ok
//  - mfma3 D (v40-43) read at cvtpk v52: 2 cvtpk(4) + s_nop7+3(13) = 17 ok
//  - mfma4 D read: 2x s_nop7 = 16 ok
//  - every VALU->MFMA operand edge has s_nop 1 (2 cyc) minimum.
__device__ __forceinline__ void tree4(s16x4 l0, s16x4 l1, s16x4 l2, s16x4 l3,
                                      s16x4 vv, f32x4 z, u32& vo0, u32& vo1){
  asm volatile(
    "s_nop 1\n\t"
    "v_mfma_f32_16x16x16_bf16 v[40:43], %[l0], %[l1], %[z]\n\t"
    "v_mfma_f32_16x16x16_bf16 v[44:47], %[l2], %[l3], %[z]\n\t"
    "s_nop 7\n\t"
    "s_nop 7\n\t"
    "v_cvt_pk_bf16_f32 v48, v40, v41\n\t"
    "v_cvt_pk_bf16_f32 v49, v42, v43\n\t"
    "s_nop 1\n\t"
    "v_mfma_f32_16x16x16_bf16 v[40:43], v[48:49], %[vv], %[z]\n\t"
    "v_cvt_pk_bf16_f32 v50, v44, v45\n\t"
    "v_cvt_pk_bf16_f32 v51, v46, v47\n\t"
    "s_nop 7\n\t"
    "s_nop 3\n\t"
    "v_cvt_pk_bf16_f32 v52, v40, v41\n\t"
    "v_cvt_pk_bf16_f32 v53, v42, v43\n\t"
    "s_nop 1\n\t"
    "v_mfma_f32_16x16x16_bf16 v[44:47], v[50:51], v[52:53], %[z]\n\t"
    "s_nop 7\n\t"
    "s_nop 7\n\t"
    "v_cvt_pk_bf16_f32 %[o0], v44, v45\n\t"
    "v_cvt_pk_bf16_f32 %[o1], v46, v47"
    : [o0]"=&v"(vo0), [o1]"=&v"(vo1)
    : [l0]"v"(l0), [l1]"v"(l1), [l2]"v"(l2), [l3]"v"(l3),
      [vv]"v"(vv), [z]"v"(z)
    : "v40","v41","v42","v43","v44","v45","v46","v47",
      "v48","v49","v50","v51","v52","v53");
}

__global__ __launch_bounds__(256) void k_zero(float* lenw, float* Sw, float* out){
  int i = blockIdx.x*256 + threadIdx.x;
  if (i < Bsz) lenw[i] = 0.f;
  else if (i < 2*Bsz) Sw[i - Bsz] = 0.f;
  if (i == 0) out[0] = 0.f;
}

// lengths[b] = sum_t mask[t,b]; S[b] partial = sum_t trans[y0[t+1],y0[t]]*mask[t]
__global__ __launch_bounds__(256) void k_score(const int* __restrict__ y0,
    const float* __restrict__ mask, const float* __restrict__ trans,
    float* __restrict__ lenw, float* __restrict__ Sw){
  __shared__ float Tt[256];
  Tt[threadIdx.x] = trans[threadIdx.x];
  __syncthreads();
  int gid = blockIdx.x*256 + threadIdx.x;   // 65536 threads: b fast, tc slow
  int b  = gid & (Bsz-1);
  int tc = gid >> 11;                        // 0..31, 32 t's each
  int t0 = tc * 32;
  float lacc = 0.f, sacc = 0.f;
  int yc = y0[t0*Bsz + b];
  #pragma unroll 4
  for (int t = t0; t < t0+32; ++t) {
    float m = mask[t*Bsz + b];
    int yn = y0[(t+1)*Bsz + b];
    lacc += m;
    if (t <= Lsz-2) sacc += m * Tt[yn*16 + yc];
    yc = yn;
  }
  atomicAdd(&lenw[b], lacc);
  atomicAdd(&Sw[b], sacc);
}

// Phase 1: wave wid = bid*4+warp; c = wid>>11 (chunk-major), b = wid&2047.
__global__ __launch_bounds__(256) void k_phase1(const float* __restrict__ h,
    const float* __restrict__ trans, const float* __restrict__ lenw,
    u32x2* __restrict__ Pout){
  // per-warp g tile, f32 [t][tag], row stride 20 (R6-proven: b128 reads at
  // t*20+4grp conflict-free; b32 reads at t*20+cl conflict-free broadcast).
  __shared__ __align__(16) float gbuf[4][65*GSTR];
  int warp = threadIdx.x >> 6;
  int wid  = blockIdx.x*4 + warp;
  int c    = wid >> 11;          // 0..15 chunk (chunk-major across grid)
  int b    = wid & (Bsz-1);
  int lane = threadIdx.x & 63;
  int cl   = lane & 15;
  int grp  = lane >> 4;
  int t0   = c << 6;
  int len  = (int)(lenw[b] + 0.5f);
  int active = len - t0;
  if (active <= 0) return;
  if (active > 64) active = 64;

  // ---- stage g = exp(sigmoid(h)) f32 (R6-verbatim).
  {
    const float* hp = h + (size_t)(t0 + grp)*BT + b*16 + cl;
    float* wp = &gbuf[warp][0];
    #pragma unroll
    for (int i = 0; i < 16; ++i) {
      float hv = hp[(size_t)(4*i)*BT];
      float sg = rcpx(1.f + exp2x(hv * (-LOG2E)));
      wp[(4*i + grp)*GSTR + cl] = exp2x(sg * LOG2E);
    }
  }

  // E fragments, f32, scaled 2^-4. EA[j] = E[cl][k0+j] (A-layout row cl);
  // EB[j] = E[k0+j][cl] (B-layout col cl). exp(NEG) underflows to exact 0.
  int k0 = grp*4;
  float EA0, EA1, EA2, EA3, EB0, EB1, EB2, EB3;
  {
    const float* tpA = trans + cl*16 + k0;
    EA0 = exp2x(tpA[0]*LOG2E) * 0.0625f;
    EA1 = exp2x(tpA[1]*LOG2E) * 0.0625f;
    EA2 = exp2x(tpA[2]*LOG2E) * 0.0625f;
    EA3 = exp2x(tpA[3]*LOG2E) * 0.0625f;
    EB0 = exp2x(trans[(k0+0)*16 + cl]*LOG2E) * 0.0625f;
    EB1 = exp2x(trans[(k0+1)*16 + cl]*LOG2E) * 0.0625f;
    EB2 = exp2x(trans[(k0+2)*16 + cl]*LOG2E) * 0.0625f;
    EB3 = exp2x(trans[(k0+3)*16 + cl]*LOG2E) * 0.0625f;
  }
  union { u32 u[2]; s16x4 v; } EApk;
  EApk.u[0] = cvtpk_bf16(EA0, EA1);
  EApk.u[1] = cvtpk_bf16(EA2, EA3);

  // Running V (B-frag), init = identity.
  u32 bx = ((k0+0)==cl ? 0x3F80u : 0u) | (((k0+1)==cl ? 0x3F80u : 0u) << 16);
  u32 by = ((k0+2)==cl ? 0x3F80u : 0u) | (((k0+3)==cl ? 0x3F80u : 0u) << 16);
  const f32x4 z4 = {0.f, 0.f, 0.f, 0.f};
  const float* gp = &gbuf[warp][0];

  int S = active >> 2;
  for (int s = 0; s < S; ++s) {
    int t = 4*s;
    f32x4 g0 = *(const f32x4*)(gp + (t+0)*GSTR + k0);
    float  s1 = gp[(t+1)*GSTR + cl];
    f32x4 g2 = *(const f32x4*)(gp + (t+2)*GSTR + k0);
    float  s3 = gp[(t+3)*GSTR + cl];
    union { u32 u[2]; s16x4 v; } L0, L1, L2, L3, Vv;
    // L0 = Bfrag(Em_t) = EB*g4 ; L1 = Afrag(Em_{t+1}) = EA*g[t+1][cl]
    L0.u[0] = cvtpk_bf16(EB0*g0.x, EB1*g0.y);
    L0.u[1] = cvtpk_bf16(EB2*g0.z, EB3*g0.w);
    L1.u[0] = cvtpk_bf16(EA0*s1, EA1*s1);
    L1.u[1] = cvtpk_bf16(EA2*s1, EA3*s1);
    L2.u[0] = cvtpk_bf16(EB0*g2.x, EB1*g2.y);
    L2.u[1] = cvtpk_bf16(EB2*g2.z, EB3*g2.w);
    L3.u[0] = cvtpk_bf16(EA0*s3, EA1*s3);
    L3.u[1] = cvtpk_bf16(EA2*s3, EA3*s3);
    Vv.u[0] = bx; Vv.u[1] = by;
    tree4(L0.v, L1.v, L2.v, L3.v, Vv.v, z4, bx, by);
  }
  // tail (<=3 single steps, R6-proven form: V' = g4 o (E*V))
  for (int s = 4*S; s < active; ++s) {
    f32x4 g4 = *(const f32x4*)(gp + s*GSTR + k0);
    union { u32 u[2]; s16x4 v; } Bf;
    Bf.u[0] = bx; Bf.u[1] = by;
    f32x4 d = mfma16(EApk.v, Bf.v, z4);
    bx = cvtpk_bf16(d.x*g4.x, d.y*g4.y);
    by = cvtpk_bf16(d.z*g4.z, d.w*g4.w);
  }

  Pout[(size_t)(b*16 + c)*64 + lane] = (u32x2){bx, by};
}

// Phase 2: wave per b. v <- P_c * v with power-of-2 renorm; then final lse.
__global__ __launch_bounds__(256) void k_phase2(const u32x2* __restrict__ P,
    const float* __restrict__ trans, const float* __restrict__ lenw,
    const float* __restrict__ Sw, const int* __restrict__ y0,
    float* __restrict__ out){
  __shared__ float red[4];
  int b = blockIdx.x*4 + (threadIdx.x >> 6);
  int lane = threadIdx.x & 63;
  int cl = lane & 15, grp = lane >> 4;
  int len = (int)(lenw[b] + 0.5f);
  float v = (cl == 1) ? 1.f : 0.f;    // exp(Z0): one-hot at SOS_IDX=1
  float lsc = 0.f;                    // accumulated log2 scale
  int nch = (len + 63) >> 6;
  const u32x2* Pb = P + (size_t)b*16*64;
  int srcaddr = (cl >> 2) << 6;       // bpermute byte addr of lane (cl>>2)*16
  int msel = cl & 3;
  for (int c = 0; c < nch; ++c) {
    u32x2 pw = Pb[c*64 + lane];       // P[grp*4+m, cl] bf16 pairs
    float p0 = __uint_as_float(pw.x << 16);
    float p1 = __uint_as_float(pw.x & 0xffff0000u);
    float p2 = __uint_as_float(pw.y << 16);
    float p3 = __uint_as_float(pw.y & 0xffff0000u);
    float q0 = p0*v, q1 = p1*v, q2 = p2*v, q3 = p3*v;
    #pragma unroll
    for (int mk = 1; mk <= 8; mk <<= 1) {
      q0 += __shfl_xor(q0, mk);
      q1 += __shfl_xor(q1, mk);
      q2 += __shfl_xor(q2, mk);
      q3 += __shfl_xor(q3, mk);
    }
    float t0v = __int_as_float(__builtin_amdgcn_ds_bpermute(srcaddr, __float_as_int(q0)));
    float t1v = __int_as_float(__builtin_amdgcn_ds_bpermute(srcaddr, __float_as_int(q1)));
    float t2v = __int_as_float(__builtin_amdgcn_ds_bpermute(srcaddr, __float_as_int(q2)));
    float t3v = __int_as_float(__builtin_amdgcn_ds_bpermute(srcaddr, __float_as_int(q3)));
    float vn = (msel==0) ? t0v : (msel==1) ? t1v : (msel==2) ? t2v : t3v;
    float gm = fmaxf(fmaxf(q0,q1), fmaxf(q2,q3));
    gm = fmaxf(gm, __shfl_xor(gm, 16));
    gm = fmaxf(gm, __shfl_xor(gm, 32));
    int eb = (int)((__float_as_uint(gm) >> 23) & 0xff) - 127;
    float sc = __uint_as_float((u32)(127 - eb) << 23);
    v = vn * sc;
    lsc += (float)eb;
  }
  float eE = exp2x(trans[32 + cl] * LOG2E);
  float num = v * eE;
  num += __shfl_xor(num, 1);
  num += __shfl_xor(num, 2);
  num += __shfl_xor(num, 4);
  num += __shfl_xor(num, 8);
  if (lane == 0) {
    float Z = (log2x(num) + lsc + 4.f*(float)len) * LN2;
    int lastTag = y0[(size_t)len*Bsz + b];
    float Sb = Sw[b] + trans[lastTag];     // trans[PAD=0, lastTag]
    red[threadIdx.x >> 6] = (Z - Sb) * (1.f/(float)Bsz);
  }
  __syncthreads();
  if (threadIdx.x == 0) {
    atomicAdd(out, red[0] + red[1] + red[2] + red[3]);
  }
}

extern "C" void kernel_launch(void* const* d_in, const int* in_sizes, int n_in,
                              void* d_out, int out_size, void* d_ws, size_t ws_size,
                              hipStream_t stream) {
  const float* h     = (const float*)d_in[0];
  const int*   y0    = (const int*)d_in[1];
  const float* mask  = (const float*)d_in[2];
  const float* trans = (const float*)d_in[3];
  float* out  = (float*)d_out;
  float* lenw = (float*)d_ws;
  float* Sw   = lenw + Bsz;
  u32x2* P    = (u32x2*)((char*)d_ws + 16384);

  k_zero  <<<16,   256, 0, stream>>>(lenw, Sw, out);
  k_score <<<256,  256, 0, stream>>>(y0, mask, trans, lenw, Sw);
  k_phase1<<<8192, 256, 0, stream>>>(h, trans, lenw, P);
  k_phase2<<<512,  256, 0, stream>>>(P, trans, lenw, Sw, y0, out);
}